// Round 5
// baseline (328.130 us; speedup 1.0000x reference)
//
#include <hip/hip_runtime.h>
#include <math.h>

#define S 256
#define NPIX (S * S)          // 65536
#define B 64
#define NQUAD 16
#define BLK_PER_BATCH 32
#define GRID_BLOCKS (B * BLK_PER_BATCH)   // 2048

typedef float vfloat4 __attribute__((ext_vector_type(4)));

// d_ws layout: params [B][12] floats at offset 0; flags [B] uint at offset 4096.
// Harness poisons d_ws to 0xAA before every launch -> flags != 1 at entry.

struct SolveSmem {
    double sp[64][3];          // kpt_src
    double sq[64][3];          // kpt_dst
    double sR[NQUAD][9];
    double sT[NQUAD][3];
    double sw[NQUAD];
    int    scol[64];
};

// Full f64 pose solve for batch b; all 256 threads of the block enter
// (contains __syncthreads). Result in sprm[12] = {R_p row-major, T_p}.
__device__ __forceinline__ void solve_pose(
    SolveSmem& sm, float* sprm,
    const float* __restrict__ Offset, const float* __restrict__ Posmap,
    const float* __restrict__ meanp,  const int* __restrict__ uv,
    int b, int t)
{
    if (t < 64) {
        const int u = uv[2 * t + 0];
        const int v = uv[2 * t + 1];
        sm.scol[t] = v;
        const int n = u * S + v;
        const float* offb = Offset + (size_t)b * 3 * NPIX;
        const float* posb = Posmap + (size_t)b * 3 * NPIX;
#pragma unroll
        for (int c = 0; c < 3; ++c) {
            sm.sp[t][c] = (double)offb[c * NPIX + n] * 6.0 + (double)meanp[c * NPIX + n];
            sm.sq[t][c] = (double)posb[c * NPIX + n];
        }
    }
    __syncthreads();

    if (t < NQUAD) {
        const int k0 = 4 * t;
        double A[3][3], Bm[3][3];
#pragma unroll
        for (int r = 0; r < 3; ++r)
#pragma unroll
            for (int c = 0; c < 3; ++c) {
                A[r][c]  = sm.sp[k0][c] - sm.sp[k0 + 1 + r][c];
                Bm[r][c] = sm.sq[k0][c] - sm.sq[k0 + 1 + r][c];
            }
        const double c00 = A[1][1] * A[2][2] - A[1][2] * A[2][1];
        const double c01 = A[1][2] * A[2][0] - A[1][0] * A[2][2];
        const double c02 = A[1][0] * A[2][1] - A[1][1] * A[2][0];
        const double det = A[0][0] * c00 + A[0][1] * c01 + A[0][2] * c02;
        const double id  = 1.0 / det;
        double inv[3][3];
        inv[0][0] = c00 * id;
        inv[0][1] = (A[0][2] * A[2][1] - A[0][1] * A[2][2]) * id;
        inv[0][2] = (A[0][1] * A[1][2] - A[0][2] * A[1][1]) * id;
        inv[1][0] = c01 * id;
        inv[1][1] = (A[0][0] * A[2][2] - A[0][2] * A[2][0]) * id;
        inv[1][2] = (A[0][2] * A[1][0] - A[0][0] * A[1][2]) * id;
        inv[2][0] = c02 * id;
        inv[2][1] = (A[0][1] * A[2][0] - A[0][0] * A[2][1]) * id;
        inv[2][2] = (A[0][0] * A[1][1] - A[0][1] * A[1][0]) * id;

        double R[3][3];
#pragma unroll
        for (int i = 0; i < 3; ++i)
#pragma unroll
            for (int j = 0; j < 3; ++j) {
                R[i][j] = inv[i][0] * Bm[0][j] + inv[i][1] * Bm[1][j] + inv[i][2] * Bm[2][j];
                sm.sR[t][i * 3 + j] = R[i][j];
            }
#pragma unroll
        for (int c = 0; c < 3; ++c) {
            double acc = 0.0;
#pragma unroll
            for (int j = 0; j < 4; ++j) {
                const double pr = sm.sp[k0 + j][0] * R[0][c] +
                                  sm.sp[k0 + j][1] * R[1][c] +
                                  sm.sp[k0 + j][2] * R[2][c];
                acc += sm.sq[k0 + j][c] - pr;
            }
            sm.sT[t][c] = acc * 0.25;
        }
    }
    __syncthreads();

    if (t == 0) {
        double r00 = 0.0, r10 = 0.0, r20 = 0.0;
#pragma unroll
        for (int q = 0; q < NQUAD; ++q) {
            r00 += sm.sR[q][0];
            r10 += sm.sR[q][3];
            r20 += sm.sR[q][6];
        }
        r00 /= NQUAD; r10 /= NQUAD; r20 /= NQUAD;
        const double yaw = atan2(-r20, sqrt(r00 * r00 + r10 * r10));
        const double yr  = yaw / M_PI;
        const double left  = fmax(yr * (double)S, 0.0);
        const double right = fmin((double)S + yr * (double)S, (double)S);
#pragma unroll
        for (int q = 0; q < NQUAD; ++q) {
            double wq = 1.0;
#pragma unroll
            for (int j = 0; j < 4; ++j) {
                const double col = (double)sm.scol[4 * q + j];
                wq *= (col <= left || col >= right) ? 0.001 : 1.0;
            }
            sm.sw[q] = wq;
        }
    }
    __syncthreads();

    if (t < 12) {
        double s = 0.0;
#pragma unroll
        for (int q = 0; q < NQUAD; ++q) s += sm.sw[q];
        double acc = 0.0;
        if (t < 9) {
#pragma unroll
            for (int q = 0; q < NQUAD; ++q) acc += sm.sw[q] * sm.sR[q][t];
        } else {
#pragma unroll
            for (int q = 0; q < NQUAD; ++q) acc += sm.sw[q] * sm.sT[q][t - 9];
        }
        sprm[t] = (float)(acc / s);
    }
    __syncthreads();
}

// ---------------------------------------------------------------------------
// Fused single-launch kernel. Block (b,jb): jb==0 solves batch b's pose and
// publishes params+flag (device scope); jb>0 prefetches its streaming loads,
// then bounded-spins on the flag (fallback: solve locally -> no deadlock,
// bit-identical values). Then all blocks stream their 512-group slice
// (2 float4 groups/thread).
// ---------------------------------------------------------------------------
__global__ __launch_bounds__(256) void visible_rebuild_fused(
    const float* __restrict__ Offset,      // [B][3][NPIX]
    const float* __restrict__ Posmap,      // [B][3][NPIX]
    const float* __restrict__ meanp,       // [3][NPIX]
    const int*   __restrict__ uv,          // [68][2]
    float*       __restrict__ params,      // d_ws: [B][12]
    unsigned*    __restrict__ flags,       // d_ws+4096: [B]
    float*       __restrict__ out)         // [B][3][NPIX]
{
    __shared__ SolveSmem sm;
    __shared__ float sprm[12];
    __shared__ int   sok;

    const int bk = blockIdx.x;
    const int b  = bk >> 5;                // batch
    const int jb = bk & (BLK_PER_BATCH - 1);
    const int t  = threadIdx.x;

    const float* offb = Offset + (size_t)b * 3 * NPIX;
    const int n0 = ((jb * 512 + t) << 2);  // group 0 pixel base
    const int n1 = n0 + 1024;              // group 1 pixel base (+256 groups)

    // ---- prefetch group-0 streaming loads (in flight during solve/spin) ----
    const vfloat4 o0a = __builtin_nontemporal_load((const vfloat4*)(offb + 0 * NPIX + n0));
    const vfloat4 o1a = __builtin_nontemporal_load((const vfloat4*)(offb + 1 * NPIX + n0));
    const vfloat4 o2a = __builtin_nontemporal_load((const vfloat4*)(offb + 2 * NPIX + n0));
    const vfloat4 m0a = *(const vfloat4*)(meanp + 0 * NPIX + n0);
    const vfloat4 m1a = *(const vfloat4*)(meanp + 1 * NPIX + n0);
    const vfloat4 m2a = *(const vfloat4*)(meanp + 2 * NPIX + n0);

    if (jb == 0) {
        // ---- solver block: compute pose, publish ----
        solve_pose(sm, sprm, Offset, Posmap, meanp, uv, b, t);
        if (t < 12)
            __hip_atomic_store(&params[b * 12 + t], sprm[t],
                               __ATOMIC_RELAXED, __HIP_MEMORY_SCOPE_AGENT);
        __syncthreads();
        if (t == 0)
            __hip_atomic_store(&flags[b], 1u,
                               __ATOMIC_RELEASE, __HIP_MEMORY_SCOPE_AGENT);
    } else {
        // ---- consumer block: bounded spin, fallback = local solve ----
        if (t == 0) {
            unsigned f = 0;
            for (int it = 0; it < 30000; ++it) {
                f = __hip_atomic_load(&flags[b],
                                      __ATOMIC_ACQUIRE, __HIP_MEMORY_SCOPE_AGENT);
                if (f == 1u) break;
                __builtin_amdgcn_s_sleep(2);
            }
            sok = (f == 1u);
        }
        __syncthreads();
        if (sok) {
            if (t < 12)
                sprm[t] = __hip_atomic_load(&params[b * 12 + t],
                                            __ATOMIC_RELAXED, __HIP_MEMORY_SCOPE_AGENT);
            __syncthreads();
        } else {
            solve_pose(sm, sprm, Offset, Posmap, meanp, uv, b, t);
        }
    }

    const float r00 = sprm[0], r01 = sprm[1], r02 = sprm[2];
    const float r10 = sprm[3], r11 = sprm[4], r12 = sprm[5];
    const float r20 = sprm[6], r21 = sprm[7], r22 = sprm[8];
    const float t0 = sprm[9], t1 = sprm[10], t2 = sprm[11];
    float* outb = out + (size_t)b * 3 * NPIX;

    // ---- group 0 (prefetched) ----
    {
        const vfloat4 x = o0a * 6.f + m0a;
        const vfloat4 y = o1a * 6.f + m1a;
        const vfloat4 z = o2a * 6.f + m2a;
        const vfloat4 u  = x * r00 + y * r10 + z * r20 + t0;
        const vfloat4 v  = x * r01 + y * r11 + z * r21 + t1;
        const vfloat4 wv = x * r02 + y * r12 + z * r22 + t2;
        __builtin_nontemporal_store(u,  (vfloat4*)(outb + 0 * NPIX + n0));
        __builtin_nontemporal_store(v,  (vfloat4*)(outb + 1 * NPIX + n0));
        __builtin_nontemporal_store(wv, (vfloat4*)(outb + 2 * NPIX + n0));
    }
    // ---- group 1 ----
    {
        const vfloat4 o0 = __builtin_nontemporal_load((const vfloat4*)(offb + 0 * NPIX + n1));
        const vfloat4 o1 = __builtin_nontemporal_load((const vfloat4*)(offb + 1 * NPIX + n1));
        const vfloat4 o2 = __builtin_nontemporal_load((const vfloat4*)(offb + 2 * NPIX + n1));
        const vfloat4 m0 = *(const vfloat4*)(meanp + 0 * NPIX + n1);
        const vfloat4 m1 = *(const vfloat4*)(meanp + 1 * NPIX + n1);
        const vfloat4 m2 = *(const vfloat4*)(meanp + 2 * NPIX + n1);
        const vfloat4 x = o0 * 6.f + m0;
        const vfloat4 y = o1 * 6.f + m1;
        const vfloat4 z = o2 * 6.f + m2;
        const vfloat4 u  = x * r00 + y * r10 + z * r20 + t0;
        const vfloat4 v  = x * r01 + y * r11 + z * r21 + t1;
        const vfloat4 wv = x * r02 + y * r12 + z * r22 + t2;
        __builtin_nontemporal_store(u,  (vfloat4*)(outb + 0 * NPIX + n1));
        __builtin_nontemporal_store(v,  (vfloat4*)(outb + 1 * NPIX + n1));
        __builtin_nontemporal_store(wv, (vfloat4*)(outb + 2 * NPIX + n1));
    }
}

extern "C" void kernel_launch(void* const* d_in, const int* in_sizes, int n_in,
                              void* d_out, int out_size, void* d_ws, size_t ws_size,
                              hipStream_t stream) {
    const float* Offset = (const float*)d_in[0];   // [64][3][256][256]
    const float* Posmap = (const float*)d_in[1];   // [64][3][256][256]
    const float* meanp  = (const float*)d_in[2];   // [3][256][256]
    const int*   uv     = (const int*)d_in[3];     // [68][2]
    float* out = (float*)d_out;
    float*    params = (float*)d_ws;                       // [64][12]
    unsigned* flags  = (unsigned*)((char*)d_ws + 4096);    // [64]

    visible_rebuild_fused<<<GRID_BLOCKS, 256, 0, stream>>>(
        Offset, Posmap, meanp, uv, params, flags, out);
}